// Round 1
// baseline (288.589 us; speedup 1.0000x reference)
//
#include <hip/hip_runtime.h>
#include <math.h>

#define BB 8
#define CC 1024
#define PP 4096   // H*W = 64*64
#define KK 16
#define EPSF 1e-8f

// ws layout:
//   num     [B][K][C]  @ 0          (512 KiB)   (c-contiguous)
//   pn      [B][K]     @ 0x80000    (512 B)
//   proto_t [B][C][K]  @ 0x100000   (512 KiB)   (k-contiguous for k_match)

// ---- kernel 1: masked per-class channel sums (prototype numerators) ----
// grid 512 = B(8) x cgroup(64); block 256 = 4 waves; wave handles 4 channels
// (mask compare+select amortized over 4 fmas -> 24 VALU ops/element vs 32 at
// 2 channels/wave). Lanes cover pixels via float4/int4. 2 blocks/CU.
__global__ __launch_bounds__(256) void k_num(const float* __restrict__ sf,
                                             const int* __restrict__ sm,
                                             float* __restrict__ num) {
    int b    = blockIdx.x >> 6;
    int cg   = blockIdx.x & 63;
    int w    = threadIdx.x >> 6;
    int lane = threadIdx.x & 63;
    int c0   = cg * 16 + w * 4;

    const float4* f0 = (const float4*)(sf + ((size_t)b * CC + c0) * PP);
    const float4* f1 = (const float4*)(sf + ((size_t)b * CC + c0 + 1) * PP);
    const float4* f2 = (const float4*)(sf + ((size_t)b * CC + c0 + 2) * PP);
    const float4* f3 = (const float4*)(sf + ((size_t)b * CC + c0 + 3) * PP);
    const int4*   m4 = (const int4*)(sm + (size_t)b * PP);

    float a0[KK], a1[KK], a2[KK], a3[KK];
#pragma unroll
    for (int k = 0; k < KK; ++k) { a0[k] = 0.f; a1[k] = 0.f; a2[k] = 0.f; a3[k] = 0.f; }

    for (int it = 0; it < PP / 256; ++it) {
        int p = it * 64 + lane;
        int4   mv = m4[p];
        float4 v0 = f0[p];
        float4 v1 = f1[p];
        float4 v2 = f2[p];
        float4 v3 = f3[p];

        auto px = [&](int m_, float x0, float x1, float x2, float x3) {
#pragma unroll
            for (int k = 0; k < KK; ++k) {
                float pr = (m_ == k + 1) ? 1.0f : 0.0f;   // cmp + cndmask, shared x4
                a0[k] = fmaf(pr, x0, a0[k]);
                a1[k] = fmaf(pr, x1, a1[k]);
                a2[k] = fmaf(pr, x2, a2[k]);
                a3[k] = fmaf(pr, x3, a3[k]);
            }
        };
        px(mv.x, v0.x, v1.x, v2.x, v3.x);
        px(mv.y, v0.y, v1.y, v2.y, v3.y);
        px(mv.z, v0.z, v1.z, v2.z, v3.z);
        px(mv.w, v0.w, v1.w, v2.w, v3.w);
    }

#pragma unroll
    for (int k = 0; k < KK; ++k) {
#pragma unroll
        for (int s = 32; s >= 1; s >>= 1) {
            a0[k] += __shfl_xor(a0[k], s, 64);
            a1[k] += __shfl_xor(a1[k], s, 64);
            a2[k] += __shfl_xor(a2[k], s, 64);
            a3[k] += __shfl_xor(a3[k], s, 64);
        }
    }

    if (lane == 0) {
        // num[b][k][c]
        float* o = num + (size_t)b * KK * CC + c0;
#pragma unroll
        for (int k = 0; k < KK; ++k) {
            o[(size_t)k * CC]     = a0[k];
            o[(size_t)k * CC + 1] = a1[k];
            o[(size_t)k * CC + 2] = a2[k];
            o[(size_t)k * CC + 3] = a3[k];
        }
    }
}

// ---- kernel 2: per-(b,k) denominator + prototype + norm ----
// grid 128 = B(8) x K(16); block 256. Phase 1 counts the mask for class k
// (128 KiB mask is L2-hot after k_num). Phase 2: float4-coalesced read of
// num[b][k][:], IEEE div, transposed write to proto_t[b][c][k], norm reduce.
__global__ __launch_bounds__(256) void k_proto(const float* __restrict__ num,
                                               const int* __restrict__ sm,
                                               float* __restrict__ proto_t,
                                               float* __restrict__ pn) {
    int b    = blockIdx.x >> 4;
    int k    = blockIdx.x & 15;
    int tid  = threadIdx.x;
    int lane = tid & 63;
    int wv   = tid >> 6;

    // --- phase 1: den = count(mask == k+1) over 4096 pixels (exact: ints < 2^24)
    const int4* m4 = (const int4*)(sm + (size_t)b * PP);
    float cnt = 0.f;
#pragma unroll
    for (int i = 0; i < 4; ++i) {
        int4 mv = m4[i * 256 + tid];
        cnt += (mv.x == k + 1) ? 1.f : 0.f;
        cnt += (mv.y == k + 1) ? 1.f : 0.f;
        cnt += (mv.z == k + 1) ? 1.f : 0.f;
        cnt += (mv.w == k + 1) ? 1.f : 0.f;
    }
#pragma unroll
    for (int s = 32; s >= 1; s >>= 1) cnt += __shfl_xor(cnt, s, 64);

    __shared__ float cred[4];
    __shared__ float den_s;
    if (lane == 0) cred[wv] = cnt;
    __syncthreads();
    if (tid == 0) den_s = cred[0] + cred[1] + cred[2] + cred[3];
    __syncthreads();
    float d = den_s;

    // --- phase 2: proto = num/den (elementwise IEEE div, matches numpy), norm
    const float4* nu = (const float4*)(num + (size_t)(b * KK + k) * CC);
    float4 n4 = nu[tid];
    float4 pv;
    pv.x = n4.x / d; pv.y = n4.y / d; pv.z = n4.z / d; pv.w = n4.w / d;

    int c = tid * 4;
    float* pt = proto_t + ((size_t)b * CC + c) * KK + k;
    pt[0]      = pv.x;
    pt[KK]     = pv.y;
    pt[2 * KK] = pv.z;
    pt[3 * KK] = pv.w;

    float sq = pv.x * pv.x;
    sq = fmaf(pv.y, pv.y, sq);
    sq = fmaf(pv.z, pv.z, sq);
    sq = fmaf(pv.w, pv.w, sq);
#pragma unroll
    for (int s = 32; s >= 1; s >>= 1) sq += __shfl_xor(sq, s, 64);

    __shared__ float red[4];
    if (lane == 0) red[wv] = sq;
    __syncthreads();
    if (tid == 0) pn[b * KK + k] = sqrtf(red[0] + red[1] + red[2] + red[3]);
}

// ---- kernel 3: cosine similarity + argmax ----
// grid 512 = B(8) x pgroup(64) of 64 pixels; block 512 = 8 waves, wave = one
// 128-channel chunk x 64 pixels (float/lane) -> 2 blocks/CU, 16 waves/CU.
// ci-loop grouped x8: 8 q-loads in flight per wave (32 KB in flight/CU ->
// past Little's-law threshold for 6.3 TB/s at ~900cy HBM latency).
// Uniform base + lane voffset -> SADDR-form global loads.
// Protos via wave-uniform scalar loads; conflict-free LDS reduce.
__global__ __launch_bounds__(512) void k_match(const float* __restrict__ qf,
                                               const float* __restrict__ proto_t,
                                               const float* __restrict__ pn,
                                               int* __restrict__ out) {
    int b    = blockIdx.x >> 6;
    int pg   = blockIdx.x & 63;
    int tid  = threadIdx.x;
    int lane = tid & 63;
    int w    = __builtin_amdgcn_readfirstlane(tid >> 6);  // 0..7, wave-uniform
    int c0   = w * 128;
    int px0  = pg * 64;

    // uniform base; lane added at the load -> s_base + v_offset addressing
    const float* qbase = qf + ((size_t)b * CC + c0) * PP + px0;
    const float* pt    = proto_t + ((size_t)b * CC + c0) * KK;

    float dot[KK];
#pragma unroll
    for (int k = 0; k < KK; ++k) dot[k] = 0.f;
    float qs = 0.f;

    for (int ci = 0; ci < 128; ci += 8) {
        float v[8];
#pragma unroll
        for (int j = 0; j < 8; ++j)
            v[j] = qbase[(size_t)(ci + j) * PP + lane];   // all 8 issued first
        const float* pr = pt + ci * KK;
#pragma unroll
        for (int j = 0; j < 8; ++j) {
#pragma unroll
            for (int k = 0; k < KK; ++k)
                dot[k] = fmaf(pr[j * KK + k], v[j], dot[k]);
            qs = fmaf(v[j], v[j], qs);
        }
    }

    // buf[c][k][lane]: lane stride 4 B -> 2-way bank aliasing (free on CDNA4)
    __shared__ float buf[4][KK + 1][64];   // 17.4 KiB

    if (w >= 4) {
#pragma unroll
        for (int k = 0; k < KK; ++k) buf[w - 4][k][lane] = dot[k];
        buf[w - 4][KK][lane] = qs;
    }
    __syncthreads();
    if (w < 4) {
#pragma unroll
        for (int k = 0; k < KK; ++k) buf[w][k][lane] += dot[k];
        buf[w][KK][lane] += qs;
    }
    __syncthreads();

    if (tid < 64) {
        int px = tid;
        float q2s = 0.f;
#pragma unroll
        for (int c = 0; c < 4; ++c) q2s += buf[c][KK][px];
        float qn = sqrtf(q2s);

        float bv = -INFINITY;
        int   bi = 0;
#pragma unroll
        for (int k = 0; k < KK; ++k) {
            float dk = 0.f;
#pragma unroll
            for (int c = 0; c < 4; ++c) dk += buf[c][k][px];
            float s = dk / fmaxf(pn[b * KK + k] * qn, EPSF);
            if (s > bv) { bv = s; bi = k; }   // strict '>' = first-max (jnp.argmax)
        }
        out[(size_t)b * PP + px0 + px] = bi;
    }
}

extern "C" void kernel_launch(void* const* d_in, const int* in_sizes, int n_in,
                              void* d_out, int out_size, void* d_ws, size_t ws_size,
                              hipStream_t stream) {
    const float* sf = (const float*)d_in[0];  // support_features (8,1024,64,64) f32
    const int*   sm = (const int*)d_in[1];    // support_masks    (8,1,64,64)    i32
    const float* qf = (const float*)d_in[2];  // query_features   (8,1024,64,64) f32
    int* out = (int*)d_out;                   // (8,64,64) i32

    char*  ws      = (char*)d_ws;
    float* num     = (float*)(ws);
    float* pn      = (float*)(ws + (512u << 10));
    float* proto_t = (float*)(ws + (1u << 20));

    hipLaunchKernelGGL(k_num,   dim3(512),  dim3(256), 0, stream, sf, sm, num);
    hipLaunchKernelGGL(k_proto, dim3(128),  dim3(256), 0, stream, num, sm, proto_t, pn);
    hipLaunchKernelGGL(k_match, dim3(512),  dim3(512), 0, stream, qf, proto_t, pn, out);
}